// Round 1
// baseline (1519.152 us; speedup 1.0000x reference)
//
#include <hip/hip_runtime.h>
#include <math.h>

#define NNODES 50000
#define CDIM 128
#define HEADS 4
#define NEG 0.2f

// ---------------- GEMM: xl = x @ W  (N x 128) @ (128 x 128) ----------------
// 64 rows/block, 256 threads, each thread 4 rows x 8 cols (cols c..c+3, c+64..c+67)
__global__ __launch_bounds__(256) void gemm_kernel(const float* __restrict__ x,
                                                   const float* __restrict__ W,
                                                   float* __restrict__ xl, int N) {
    __shared__ float xs[64][68];     // 64 rows x 64 k (+4 pad)
    __shared__ float wsh[64][128];   // 64 k x 128 cols
    const int tid = threadIdx.x;
    const int row0 = blockIdx.x * 64;
    const int tr = tid >> 4;         // 0..15 row group
    const int tc = tid & 15;         // 0..15 col group
    const int cbase = tc * 4;

    float acc[4][8];
#pragma unroll
    for (int r = 0; r < 4; ++r)
#pragma unroll
        for (int j = 0; j < 8; ++j) acc[r][j] = 0.f;

    for (int k0 = 0; k0 < 128; k0 += 64) {
        __syncthreads();
        // stage x tile: 64 rows x 64 k = 1024 float4, 4/thread
#pragma unroll
        for (int i = 0; i < 4; ++i) {
            int f = tid + i * 256;
            int r = f >> 4, k4 = f & 15;
            float4 v = make_float4(0.f, 0.f, 0.f, 0.f);
            int gr = row0 + r;
            if (gr < N) v = *(const float4*)(x + (size_t)gr * CDIM + k0 + k4 * 4);
            *(float4*)(&xs[r][k4 * 4]) = v;
        }
        // stage W tile: 64 k x 128 cols = 2048 float4, 8/thread (row-major, no transpose)
#pragma unroll
        for (int i = 0; i < 8; ++i) {
            int f = tid + i * 256;
            int kr = f >> 5, c4 = f & 31;
            float4 v = *(const float4*)(W + (size_t)(k0 + kr) * CDIM + c4 * 4);
            *(float4*)(&wsh[kr][c4 * 4]) = v;
        }
        __syncthreads();
#pragma unroll 4
        for (int kk = 0; kk < 64; ++kk) {
            float xv0 = xs[tr * 4 + 0][kk];
            float xv1 = xs[tr * 4 + 1][kk];
            float xv2 = xs[tr * 4 + 2][kk];
            float xv3 = xs[tr * 4 + 3][kk];
            float4 w0 = *(const float4*)(&wsh[kk][cbase]);
            float4 w1 = *(const float4*)(&wsh[kk][cbase + 64]);
            acc[0][0] += xv0 * w0.x; acc[0][1] += xv0 * w0.y; acc[0][2] += xv0 * w0.z; acc[0][3] += xv0 * w0.w;
            acc[0][4] += xv0 * w1.x; acc[0][5] += xv0 * w1.y; acc[0][6] += xv0 * w1.z; acc[0][7] += xv0 * w1.w;
            acc[1][0] += xv1 * w0.x; acc[1][1] += xv1 * w0.y; acc[1][2] += xv1 * w0.z; acc[1][3] += xv1 * w0.w;
            acc[1][4] += xv1 * w1.x; acc[1][5] += xv1 * w1.y; acc[1][6] += xv1 * w1.z; acc[1][7] += xv1 * w1.w;
            acc[2][0] += xv2 * w0.x; acc[2][1] += xv2 * w0.y; acc[2][2] += xv2 * w0.z; acc[2][3] += xv2 * w0.w;
            acc[2][4] += xv2 * w1.x; acc[2][5] += xv2 * w1.y; acc[2][6] += xv2 * w1.z; acc[2][7] += xv2 * w1.w;
            acc[3][0] += xv3 * w0.x; acc[3][1] += xv3 * w0.y; acc[3][2] += xv3 * w0.z; acc[3][3] += xv3 * w0.w;
            acc[3][4] += xv3 * w1.x; acc[3][5] += xv3 * w1.y; acc[3][6] += xv3 * w1.z; acc[3][7] += xv3 * w1.w;
        }
    }
#pragma unroll
    for (int r = 0; r < 4; ++r) {
        int row = row0 + tr * 4 + r;
        if (row < N) {
            float4 o0 = make_float4(acc[r][0], acc[r][1], acc[r][2], acc[r][3]);
            float4 o1 = make_float4(acc[r][4], acc[r][5], acc[r][6], acc[r][7]);
            *(float4*)(xl + (size_t)row * CDIM + cbase) = o0;
            *(float4*)(xl + (size_t)row * CDIM + cbase + 64) = o1;
        }
    }
}

// ---------------- per-node attention logits a_src/a_dst [N,4] ----------------
// one wave (64 lanes) per node; lane handles channels lane and lane+64
__global__ __launch_bounds__(256) void attn_kernel(const float* __restrict__ xl,
                                                   const float* __restrict__ att_src,
                                                   const float* __restrict__ att_dst,
                                                   float* __restrict__ a_src,
                                                   float* __restrict__ a_dst, int N) {
    int node = blockIdx.x * 4 + (threadIdx.x >> 6);
    int lane = threadIdx.x & 63;
    if (node >= N) return;
    float v0 = xl[(size_t)node * CDIM + lane];
    float v1 = xl[(size_t)node * CDIM + lane + 64];
    // att_* are [4][32] flat: channel c -> index c (h = c>>5, within = c&31)
    float ps0 = v0 * att_src[lane];
    float ps1 = v1 * att_src[lane + 64];
    float pd0 = v0 * att_dst[lane];
    float pd1 = v1 * att_dst[lane + 64];
#pragma unroll
    for (int off = 16; off > 0; off >>= 1) {
        ps0 += __shfl_down(ps0, off, 32);
        ps1 += __shfl_down(ps1, off, 32);
        pd0 += __shfl_down(pd0, off, 32);
        pd1 += __shfl_down(pd1, off, 32);
    }
    if ((lane & 31) == 0) {
        int h01 = lane >> 5;   // 0 or 1
        a_src[node * 4 + h01] = ps0;
        a_src[node * 4 + 2 + h01] = ps1;
        a_dst[node * 4 + h01] = pd0;
        a_dst[node * 4 + 2 + h01] = pd1;
    }
}

// ---------------- edge scatter: num[d] += w * xl[s], denom[d,h] += w ----------------
// 32 threads per edge, thread handles 4 consecutive channels
__global__ __launch_bounds__(256) void edge_kernel(const int* __restrict__ src,
                                                   const int* __restrict__ dst,
                                                   const float* __restrict__ xl,
                                                   const float* __restrict__ a_src,
                                                   const float* __restrict__ a_dst,
                                                   float* __restrict__ num,
                                                   float* __restrict__ denom, int E) {
    int t = blockIdx.x * 256 + threadIdx.x;
    int e = t >> 5;
    if (e >= E) return;
    int lane32 = t & 31;
    int s = src[e], d = dst[e];
    if (s == d) return;  // reference drops pre-existing self loops
    int c4 = lane32 * 4;
    int h = c4 >> 5;
    float eh = a_src[s * 4 + h] + a_dst[d * 4 + h];
    eh = eh > 0.f ? eh : NEG * eh;
    float w = __expf(eh);
    float4 xv = *(const float4*)(xl + (size_t)s * CDIM + c4);
    float* np = num + (size_t)d * CDIM + c4;
    atomicAdd(np + 0, w * xv.x);
    atomicAdd(np + 1, w * xv.y);
    atomicAdd(np + 2, w * xv.z);
    atomicAdd(np + 3, w * xv.w);
    if ((lane32 & 7) == 0) atomicAdd(denom + (size_t)d * 4 + h, w);
}

// ---------------- finalize: add self loop, normalize, bias, /sqrt(H) ----------------
__global__ __launch_bounds__(256) void final_kernel(const float* __restrict__ xl,
                                                    const float* __restrict__ num,
                                                    const float* __restrict__ denom,
                                                    const float* __restrict__ a_src,
                                                    const float* __restrict__ a_dst,
                                                    const float* __restrict__ bias,
                                                    float* __restrict__ out, int N) {
    int t = blockIdx.x * 256 + threadIdx.x;
    int n = t >> 5;
    if (n >= N) return;
    int c4 = (t & 31) * 4;
    int h = c4 >> 5;
    float eh = a_src[n * 4 + h] + a_dst[n * 4 + h];
    eh = eh > 0.f ? eh : NEG * eh;
    float wself = __expf(eh);
    float den = denom[(size_t)n * 4 + h] + wself;
    float inv = 1.0f / den;
    float4 nu = *(const float4*)(num + (size_t)n * CDIM + c4);
    float4 xv = *(const float4*)(xl + (size_t)n * CDIM + c4);
    float4 b = *(const float4*)(bias + c4);
    float4 o;
    o.x = ((nu.x + wself * xv.x) * inv + b.x) * 0.5f;
    o.y = ((nu.y + wself * xv.y) * inv + b.y) * 0.5f;
    o.z = ((nu.z + wself * xv.z) * inv + b.z) * 0.5f;
    o.w = ((nu.w + wself * xv.w) * inv + b.w) * 0.5f;
    *(float4*)(out + (size_t)n * CDIM + c4) = o;
}

extern "C" void kernel_launch(void* const* d_in, const int* in_sizes, int n_in,
                              void* d_out, int out_size, void* d_ws, size_t ws_size,
                              hipStream_t stream) {
    const float* x       = (const float*)d_in[0];
    const int*   ei      = (const int*)d_in[1];
    const float* W       = (const float*)d_in[2];
    const float* att_src = (const float*)d_in[3];
    const float* att_dst = (const float*)d_in[4];
    const float* bias    = (const float*)d_in[5];
    float* out = (float*)d_out;

    const int N = in_sizes[0] / CDIM;   // 50000
    const int E = in_sizes[1] / 2;      // 800000

    float* ws    = (float*)d_ws;
    float* xl    = ws;                          // N*128
    float* num   = xl + (size_t)N * CDIM;       // N*128
    float* a_src = num + (size_t)N * CDIM;      // N*4
    float* a_dst = a_src + (size_t)N * HEADS;   // N*4
    float* denom = a_dst + (size_t)N * HEADS;   // N*4

    hipMemsetAsync(num, 0, (size_t)N * CDIM * sizeof(float), stream);
    hipMemsetAsync(denom, 0, (size_t)N * HEADS * sizeof(float), stream);

    gemm_kernel<<<(N + 63) / 64, 256, 0, stream>>>(x, W, xl, N);
    attn_kernel<<<(N + 3) / 4, 256, 0, stream>>>(xl, att_src, att_dst, a_src, a_dst, N);
    edge_kernel<<<((size_t)E * 32 + 255) / 256, 256, 0, stream>>>(ei, ei + E, xl, a_src, a_dst, num, denom, E);
    final_kernel<<<((size_t)N * 32 + 255) / 256, 256, 0, stream>>>(xl, num, denom, a_src, a_dst, bias, out, N);
}

// Round 2
// 427.439 us; speedup vs baseline: 3.5541x; 3.5541x over previous
//
#include <hip/hip_runtime.h>
#include <math.h>

#define CDIM 128
#define HEADS 4
#define NEG 0.2f

// ---------------- GEMM: xl = x @ W  (N x 128) @ (128 x 128) ----------------
__global__ __launch_bounds__(256) void gemm_kernel(const float* __restrict__ x,
                                                   const float* __restrict__ W,
                                                   float* __restrict__ xl, int N) {
    __shared__ float xs[64][68];
    __shared__ float wsh[64][128];
    const int tid = threadIdx.x;
    const int row0 = blockIdx.x * 64;
    const int tr = tid >> 4;
    const int tc = tid & 15;
    const int cbase = tc * 4;

    float acc[4][8];
#pragma unroll
    for (int r = 0; r < 4; ++r)
#pragma unroll
        for (int j = 0; j < 8; ++j) acc[r][j] = 0.f;

    for (int k0 = 0; k0 < 128; k0 += 64) {
        __syncthreads();
#pragma unroll
        for (int i = 0; i < 4; ++i) {
            int f = tid + i * 256;
            int r = f >> 4, k4 = f & 15;
            float4 v = make_float4(0.f, 0.f, 0.f, 0.f);
            int gr = row0 + r;
            if (gr < N) v = *(const float4*)(x + (size_t)gr * CDIM + k0 + k4 * 4);
            *(float4*)(&xs[r][k4 * 4]) = v;
        }
#pragma unroll
        for (int i = 0; i < 8; ++i) {
            int f = tid + i * 256;
            int kr = f >> 5, c4 = f & 31;
            float4 v = *(const float4*)(W + (size_t)(k0 + kr) * CDIM + c4 * 4);
            *(float4*)(&wsh[kr][c4 * 4]) = v;
        }
        __syncthreads();
#pragma unroll 4
        for (int kk = 0; kk < 64; ++kk) {
            float xv0 = xs[tr * 4 + 0][kk];
            float xv1 = xs[tr * 4 + 1][kk];
            float xv2 = xs[tr * 4 + 2][kk];
            float xv3 = xs[tr * 4 + 3][kk];
            float4 w0 = *(const float4*)(&wsh[kk][cbase]);
            float4 w1 = *(const float4*)(&wsh[kk][cbase + 64]);
            acc[0][0] += xv0 * w0.x; acc[0][1] += xv0 * w0.y; acc[0][2] += xv0 * w0.z; acc[0][3] += xv0 * w0.w;
            acc[0][4] += xv0 * w1.x; acc[0][5] += xv0 * w1.y; acc[0][6] += xv0 * w1.z; acc[0][7] += xv0 * w1.w;
            acc[1][0] += xv1 * w0.x; acc[1][1] += xv1 * w0.y; acc[1][2] += xv1 * w0.z; acc[1][3] += xv1 * w0.w;
            acc[1][4] += xv1 * w1.x; acc[1][5] += xv1 * w1.y; acc[1][6] += xv1 * w1.z; acc[1][7] += xv1 * w1.w;
            acc[2][0] += xv2 * w0.x; acc[2][1] += xv2 * w0.y; acc[2][2] += xv2 * w0.z; acc[2][3] += xv2 * w0.w;
            acc[2][4] += xv2 * w1.x; acc[2][5] += xv2 * w1.y; acc[2][6] += xv2 * w1.z; acc[2][7] += xv2 * w1.w;
            acc[3][0] += xv3 * w0.x; acc[3][1] += xv3 * w0.y; acc[3][2] += xv3 * w0.z; acc[3][3] += xv3 * w0.w;
            acc[3][4] += xv3 * w1.x; acc[3][5] += xv3 * w1.y; acc[3][6] += xv3 * w1.z; acc[3][7] += xv3 * w1.w;
        }
    }
#pragma unroll
    for (int r = 0; r < 4; ++r) {
        int row = row0 + tr * 4 + r;
        if (row < N) {
            *(float4*)(xl + (size_t)row * CDIM + cbase) = make_float4(acc[r][0], acc[r][1], acc[r][2], acc[r][3]);
            *(float4*)(xl + (size_t)row * CDIM + cbase + 64) = make_float4(acc[r][4], acc[r][5], acc[r][6], acc[r][7]);
        }
    }
}

// ---------------- per-node attention logits a_src/a_dst [N,4] ----------------
__global__ __launch_bounds__(256) void attn_kernel(const float* __restrict__ xl,
                                                   const float* __restrict__ att_src,
                                                   const float* __restrict__ att_dst,
                                                   float* __restrict__ a_src,
                                                   float* __restrict__ a_dst, int N) {
    int node = blockIdx.x * 4 + (threadIdx.x >> 6);
    int lane = threadIdx.x & 63;
    if (node >= N) return;
    float v0 = xl[(size_t)node * CDIM + lane];
    float v1 = xl[(size_t)node * CDIM + lane + 64];
    float ps0 = v0 * att_src[lane];
    float ps1 = v1 * att_src[lane + 64];
    float pd0 = v0 * att_dst[lane];
    float pd1 = v1 * att_dst[lane + 64];
#pragma unroll
    for (int off = 16; off > 0; off >>= 1) {
        ps0 += __shfl_down(ps0, off, 32);
        ps1 += __shfl_down(ps1, off, 32);
        pd0 += __shfl_down(pd0, off, 32);
        pd1 += __shfl_down(pd1, off, 32);
    }
    if ((lane & 31) == 0) {
        int h01 = lane >> 5;
        a_src[node * 4 + h01] = ps0;
        a_src[node * 4 + 2 + h01] = ps1;
        a_dst[node * 4 + h01] = pd0;
        a_dst[node * 4 + 2 + h01] = pd1;
    }
}

// ---------------- CSR build: histogram of dst (self loops dropped) ----------------
__global__ __launch_bounds__(256) void hist_kernel(const int* __restrict__ src,
                                                   const int* __restrict__ dst,
                                                   int* __restrict__ counts, int E) {
    int e = blockIdx.x * 256 + threadIdx.x;
    if (e >= E) return;
    int s = src[e], d = dst[e];
    if (s != d) atomicAdd(&counts[d], 1);
}

// single-block exclusive scan over counts[N] -> offsets[N], cursor[N]
__global__ __launch_bounds__(1024) void scan_kernel(const int* __restrict__ counts,
                                                    int* __restrict__ offsets,
                                                    int* __restrict__ cursor, int N) {
    __shared__ int partial[1024];
    const int t = threadIdx.x;
    const int chunk = (N + 1023) / 1024;
    const int base = t * chunk;
    int sum = 0;
    for (int i = 0; i < chunk; ++i) {
        int idx = base + i;
        if (idx < N) sum += counts[idx];
    }
    partial[t] = sum;
    __syncthreads();
    // Hillis-Steele inclusive scan
    for (int off = 1; off < 1024; off <<= 1) {
        int v = (t >= off) ? partial[t - off] : 0;
        __syncthreads();
        partial[t] += v;
        __syncthreads();
    }
    int run = (t == 0) ? 0 : partial[t - 1];  // exclusive prefix
    for (int i = 0; i < chunk; ++i) {
        int idx = base + i;
        if (idx < N) {
            offsets[idx] = run;
            cursor[idx] = run;
            run += counts[idx];
        }
    }
}

// scatter src ids into destination buckets
__global__ __launch_bounds__(256) void scatter_kernel(const int* __restrict__ src,
                                                      const int* __restrict__ dst,
                                                      int* __restrict__ cursor,
                                                      int* __restrict__ bucket, int E) {
    int e = blockIdx.x * 256 + threadIdx.x;
    if (e >= E) return;
    int s = src[e], d = dst[e];
    if (s == d) return;
    int pos = atomicAdd(&cursor[d], 1);
    bucket[pos] = s;
}

// ---------------- gather: one wave per dst node, fused softmax+aggregate+epilogue ----------------
__global__ __launch_bounds__(256) void gather_kernel(const int* __restrict__ offsets,
                                                     const int* __restrict__ counts,
                                                     const int* __restrict__ bucket,
                                                     const float* __restrict__ xl,
                                                     const float* __restrict__ a_src,
                                                     const float* __restrict__ a_dst,
                                                     const float* __restrict__ bias,
                                                     float* __restrict__ out, int N) {
    int node = blockIdx.x * 4 + (threadIdx.x >> 6);
    int lane = threadIdx.x & 63;
    if (node >= N) return;
    int h = lane >> 5;          // head for channel c0 = lane (heads 0/1)
    // channel c1 = lane + 64 -> heads 2/3
    float ad0 = a_dst[node * 4 + h];
    float ad1 = a_dst[node * 4 + 2 + h];

    int beg = offsets[node];
    int cnt = counts[node];

    float acc0 = 0.f, acc1 = 0.f, den0 = 0.f, den1 = 0.f;
    for (int j = 0; j < cnt; ++j) {
        int s = bucket[beg + j];
        float e0 = a_src[s * 4 + h] + ad0;
        e0 = e0 > 0.f ? e0 : NEG * e0;
        float w0 = __expf(e0);
        float e1 = a_src[s * 4 + 2 + h] + ad1;
        e1 = e1 > 0.f ? e1 : NEG * e1;
        float w1 = __expf(e1);
        acc0 += w0 * xl[(size_t)s * CDIM + lane];
        acc1 += w1 * xl[(size_t)s * CDIM + lane + 64];
        den0 += w0;
        den1 += w1;
    }
    // self loop
    float es0 = a_src[node * 4 + h] + ad0;
    es0 = es0 > 0.f ? es0 : NEG * es0;
    float ws0 = __expf(es0);
    float es1 = a_src[node * 4 + 2 + h] + ad1;
    es1 = es1 > 0.f ? es1 : NEG * es1;
    float ws1 = __expf(es1);
    acc0 += ws0 * xl[(size_t)node * CDIM + lane];
    acc1 += ws1 * xl[(size_t)node * CDIM + lane + 64];
    den0 += ws0;
    den1 += ws1;

    out[(size_t)node * CDIM + lane]      = (acc0 / den0 + bias[lane]) * 0.5f;
    out[(size_t)node * CDIM + lane + 64] = (acc1 / den1 + bias[lane + 64]) * 0.5f;
}

extern "C" void kernel_launch(void* const* d_in, const int* in_sizes, int n_in,
                              void* d_out, int out_size, void* d_ws, size_t ws_size,
                              hipStream_t stream) {
    const float* x       = (const float*)d_in[0];
    const int*   ei      = (const int*)d_in[1];
    const float* W       = (const float*)d_in[2];
    const float* att_src = (const float*)d_in[3];
    const float* att_dst = (const float*)d_in[4];
    const float* bias    = (const float*)d_in[5];
    float* out = (float*)d_out;

    const int N = in_sizes[0] / CDIM;
    const int E = in_sizes[1] / 2;

    char* wsb = (char*)d_ws;
    float* xl    = (float*)wsb;                         wsb += (size_t)N * CDIM * sizeof(float);
    float* a_src = (float*)wsb;                         wsb += (size_t)N * HEADS * sizeof(float);
    float* a_dst = (float*)wsb;                         wsb += (size_t)N * HEADS * sizeof(float);
    int* counts  = (int*)wsb;                           wsb += (size_t)N * sizeof(int);
    int* offsets = (int*)wsb;                           wsb += (size_t)N * sizeof(int);
    int* cursor  = (int*)wsb;                           wsb += (size_t)N * sizeof(int);
    int* bucket  = (int*)wsb;                           wsb += (size_t)E * sizeof(int);

    hipMemsetAsync(counts, 0, (size_t)N * sizeof(int), stream);

    gemm_kernel<<<(N + 63) / 64, 256, 0, stream>>>(x, W, xl, N);
    attn_kernel<<<(N + 3) / 4, 256, 0, stream>>>(xl, att_src, att_dst, a_src, a_dst, N);
    hist_kernel<<<(E + 255) / 256, 256, 0, stream>>>(ei, ei + E, counts, E);
    scan_kernel<<<1, 1024, 0, stream>>>(counts, offsets, cursor, N);
    scatter_kernel<<<(E + 255) / 256, 256, 0, stream>>>(ei, ei + E, cursor, bucket, E);
    gather_kernel<<<(N + 3) / 4, 256, 0, stream>>>(offsets, counts, bucket, xl, a_src, a_dst, bias, out, N);
}

// Round 3
// 308.021 us; speedup vs baseline: 4.9320x; 1.3877x over previous
//
#include <hip/hip_runtime.h>
#include <math.h>

#define CDIM 128
#define HEADS 4
#define NEG 0.2f

// ---------------- GEMM: xl = x @ W  (N x 128) @ (128 x 128) ----------------
__global__ __launch_bounds__(256) void gemm_kernel(const float* __restrict__ x,
                                                   const float* __restrict__ W,
                                                   float* __restrict__ xl, int N) {
    __shared__ float xs[64][68];
    __shared__ float wsh[64][128];
    const int tid = threadIdx.x;
    const int row0 = blockIdx.x * 64;
    const int tr = tid >> 4;
    const int tc = tid & 15;
    const int cbase = tc * 4;

    float acc[4][8];
#pragma unroll
    for (int r = 0; r < 4; ++r)
#pragma unroll
        for (int j = 0; j < 8; ++j) acc[r][j] = 0.f;

    for (int k0 = 0; k0 < 128; k0 += 64) {
        __syncthreads();
#pragma unroll
        for (int i = 0; i < 4; ++i) {
            int f = tid + i * 256;
            int r = f >> 4, k4 = f & 15;
            float4 v = make_float4(0.f, 0.f, 0.f, 0.f);
            int gr = row0 + r;
            if (gr < N) v = *(const float4*)(x + (size_t)gr * CDIM + k0 + k4 * 4);
            *(float4*)(&xs[r][k4 * 4]) = v;
        }
#pragma unroll
        for (int i = 0; i < 8; ++i) {
            int f = tid + i * 256;
            int kr = f >> 5, c4 = f & 31;
            float4 v = *(const float4*)(W + (size_t)(k0 + kr) * CDIM + c4 * 4);
            *(float4*)(&wsh[kr][c4 * 4]) = v;
        }
        __syncthreads();
#pragma unroll 4
        for (int kk = 0; kk < 64; ++kk) {
            float xv0 = xs[tr * 4 + 0][kk];
            float xv1 = xs[tr * 4 + 1][kk];
            float xv2 = xs[tr * 4 + 2][kk];
            float xv3 = xs[tr * 4 + 3][kk];
            float4 w0 = *(const float4*)(&wsh[kk][cbase]);
            float4 w1 = *(const float4*)(&wsh[kk][cbase + 64]);
            acc[0][0] += xv0 * w0.x; acc[0][1] += xv0 * w0.y; acc[0][2] += xv0 * w0.z; acc[0][3] += xv0 * w0.w;
            acc[0][4] += xv0 * w1.x; acc[0][5] += xv0 * w1.y; acc[0][6] += xv0 * w1.z; acc[0][7] += xv0 * w1.w;
            acc[1][0] += xv1 * w0.x; acc[1][1] += xv1 * w0.y; acc[1][2] += xv1 * w0.z; acc[1][3] += xv1 * w0.w;
            acc[1][4] += xv1 * w1.x; acc[1][5] += xv1 * w1.y; acc[1][6] += xv1 * w1.z; acc[1][7] += xv1 * w1.w;
            acc[2][0] += xv2 * w0.x; acc[2][1] += xv2 * w0.y; acc[2][2] += xv2 * w0.z; acc[2][3] += xv2 * w0.w;
            acc[2][4] += xv2 * w1.x; acc[2][5] += xv2 * w1.y; acc[2][6] += xv2 * w1.z; acc[2][7] += xv2 * w1.w;
            acc[3][0] += xv3 * w0.x; acc[3][1] += xv3 * w0.y; acc[3][2] += xv3 * w0.z; acc[3][3] += xv3 * w0.w;
            acc[3][4] += xv3 * w1.x; acc[3][5] += xv3 * w1.y; acc[3][6] += xv3 * w1.z; acc[3][7] += xv3 * w1.w;
        }
    }
#pragma unroll
    for (int r = 0; r < 4; ++r) {
        int row = row0 + tr * 4 + r;
        if (row < N) {
            *(float4*)(xl + (size_t)row * CDIM + cbase) = make_float4(acc[r][0], acc[r][1], acc[r][2], acc[r][3]);
            *(float4*)(xl + (size_t)row * CDIM + cbase + 64) = make_float4(acc[r][4], acc[r][5], acc[r][6], acc[r][7]);
        }
    }
}

// ---------------- per-node attention logits a_src/a_dst [N,4] ----------------
__global__ __launch_bounds__(256) void attn_kernel(const float* __restrict__ xl,
                                                   const float* __restrict__ att_src,
                                                   const float* __restrict__ att_dst,
                                                   float* __restrict__ a_src,
                                                   float* __restrict__ a_dst, int N) {
    int node = blockIdx.x * 4 + (threadIdx.x >> 6);
    int lane = threadIdx.x & 63;
    if (node >= N) return;
    float v0 = xl[(size_t)node * CDIM + lane];
    float v1 = xl[(size_t)node * CDIM + lane + 64];
    float ps0 = v0 * att_src[lane];
    float ps1 = v1 * att_src[lane + 64];
    float pd0 = v0 * att_dst[lane];
    float pd1 = v1 * att_dst[lane + 64];
#pragma unroll
    for (int off = 16; off > 0; off >>= 1) {
        ps0 += __shfl_down(ps0, off, 32);
        ps1 += __shfl_down(ps1, off, 32);
        pd0 += __shfl_down(pd0, off, 32);
        pd1 += __shfl_down(pd1, off, 32);
    }
    if ((lane & 31) == 0) {
        int h01 = lane >> 5;
        a_src[node * 4 + h01] = ps0;
        a_src[node * 4 + 2 + h01] = ps1;
        a_dst[node * 4 + h01] = pd0;
        a_dst[node * 4 + 2 + h01] = pd1;
    }
}

// ---------------- CSR build: histogram of dst (self loops dropped) ----------------
__global__ __launch_bounds__(256) void hist_kernel(const int* __restrict__ src,
                                                   const int* __restrict__ dst,
                                                   int* __restrict__ counts, int E) {
    int e = blockIdx.x * 256 + threadIdx.x;
    if (e >= E) return;
    int s = src[e], d = dst[e];
    if (s != d) atomicAdd(&counts[d], 1);
}

// ---------------- device-wide exclusive scan (3 phases, 256 elems/block) ----------------
__global__ __launch_bounds__(256) void reduce_kernel(const int* __restrict__ counts,
                                                     int* __restrict__ blockSums, int N) {
    __shared__ int sh[256];
    int idx = blockIdx.x * 256 + threadIdx.x;
    sh[threadIdx.x] = (idx < N) ? counts[idx] : 0;
    __syncthreads();
    for (int off = 128; off > 0; off >>= 1) {
        if (threadIdx.x < off) sh[threadIdx.x] += sh[threadIdx.x + off];
        __syncthreads();
    }
    if (threadIdx.x == 0) blockSums[blockIdx.x] = sh[0];
}

__global__ __launch_bounds__(256) void scan_top_kernel(int* __restrict__ blockSums,
                                                       int* __restrict__ blockPrefix, int nb) {
    __shared__ int sh[256];
    int t = threadIdx.x;
    sh[t] = (t < nb) ? blockSums[t] : 0;
    __syncthreads();
    for (int off = 1; off < 256; off <<= 1) {
        int v = (t >= off) ? sh[t - off] : 0;
        __syncthreads();
        sh[t] += v;
        __syncthreads();
    }
    if (t < nb) blockPrefix[t] = (t == 0) ? 0 : sh[t - 1];
}

__global__ __launch_bounds__(256) void apply_kernel(const int* __restrict__ counts,
                                                    const int* __restrict__ blockPrefix,
                                                    int* __restrict__ offsets,
                                                    int* __restrict__ cursor, int N) {
    __shared__ int sh[256];
    int idx = blockIdx.x * 256 + threadIdx.x;
    int t = threadIdx.x;
    int c = (idx < N) ? counts[idx] : 0;
    sh[t] = c;
    __syncthreads();
    for (int off = 1; off < 256; off <<= 1) {
        int v = (t >= off) ? sh[t - off] : 0;
        __syncthreads();
        sh[t] += v;
        __syncthreads();
    }
    if (idx < N) {
        int excl = sh[t] - c + blockPrefix[blockIdx.x];
        offsets[idx] = excl;
        cursor[idx] = excl;
    }
}

// scatter src ids into destination buckets
__global__ __launch_bounds__(256) void scatter_kernel(const int* __restrict__ src,
                                                      const int* __restrict__ dst,
                                                      int* __restrict__ cursor,
                                                      int* __restrict__ bucket, int E) {
    int e = blockIdx.x * 256 + threadIdx.x;
    if (e >= E) return;
    int s = src[e], d = dst[e];
    if (s == d) return;
    int pos = atomicAdd(&cursor[d], 1);
    bucket[pos] = s;
}

// ---------------- gather: one wave per dst node, fused softmax+aggregate+epilogue ----------------
__global__ __launch_bounds__(256) void gather_kernel(const int* __restrict__ offsets,
                                                     const int* __restrict__ counts,
                                                     const int* __restrict__ bucket,
                                                     const float* __restrict__ xl,
                                                     const float* __restrict__ a_src,
                                                     const float* __restrict__ a_dst,
                                                     const float* __restrict__ bias,
                                                     float* __restrict__ out, int N) {
    int node = blockIdx.x * 4 + (threadIdx.x >> 6);
    int lane = threadIdx.x & 63;
    if (node >= N) return;
    int h = lane >> 5;
    float ad0 = a_dst[node * 4 + h];
    float ad1 = a_dst[node * 4 + 2 + h];

    int beg = offsets[node];
    int cnt = counts[node];

    float acc0 = 0.f, acc1 = 0.f, den0 = 0.f, den1 = 0.f;
    for (int j = 0; j < cnt; ++j) {
        int s = bucket[beg + j];
        float e0 = a_src[s * 4 + h] + ad0;
        e0 = e0 > 0.f ? e0 : NEG * e0;
        float w0 = __expf(e0);
        float e1 = a_src[s * 4 + 2 + h] + ad1;
        e1 = e1 > 0.f ? e1 : NEG * e1;
        float w1 = __expf(e1);
        acc0 += w0 * xl[(size_t)s * CDIM + lane];
        acc1 += w1 * xl[(size_t)s * CDIM + lane + 64];
        den0 += w0;
        den1 += w1;
    }
    // self loop
    float es0 = a_src[node * 4 + h] + ad0;
    es0 = es0 > 0.f ? es0 : NEG * es0;
    float ws0 = __expf(es0);
    float es1 = a_src[node * 4 + 2 + h] + ad1;
    es1 = es1 > 0.f ? es1 : NEG * es1;
    float ws1 = __expf(es1);
    acc0 += ws0 * xl[(size_t)node * CDIM + lane];
    acc1 += ws1 * xl[(size_t)node * CDIM + lane + 64];
    den0 += ws0;
    den1 += ws1;

    out[(size_t)node * CDIM + lane]      = (acc0 / den0 + bias[lane]) * 0.5f;
    out[(size_t)node * CDIM + lane + 64] = (acc1 / den1 + bias[lane + 64]) * 0.5f;
}

extern "C" void kernel_launch(void* const* d_in, const int* in_sizes, int n_in,
                              void* d_out, int out_size, void* d_ws, size_t ws_size,
                              hipStream_t stream) {
    const float* x       = (const float*)d_in[0];
    const int*   ei      = (const int*)d_in[1];
    const float* W       = (const float*)d_in[2];
    const float* att_src = (const float*)d_in[3];
    const float* att_dst = (const float*)d_in[4];
    const float* bias    = (const float*)d_in[5];
    float* out = (float*)d_out;

    const int N = in_sizes[0] / CDIM;
    const int E = in_sizes[1] / 2;
    const int nb = (N + 255) / 256;   // 196 for N=50000

    char* wsb = (char*)d_ws;
    float* xl    = (float*)wsb;                         wsb += (size_t)N * CDIM * sizeof(float);
    float* a_src = (float*)wsb;                         wsb += (size_t)N * HEADS * sizeof(float);
    float* a_dst = (float*)wsb;                         wsb += (size_t)N * HEADS * sizeof(float);
    int* counts  = (int*)wsb;                           wsb += (size_t)N * sizeof(int);
    int* offsets = (int*)wsb;                           wsb += (size_t)N * sizeof(int);
    int* cursor  = (int*)wsb;                           wsb += (size_t)N * sizeof(int);
    int* blockSums   = (int*)wsb;                       wsb += (size_t)nb * sizeof(int);
    int* blockPrefix = (int*)wsb;                       wsb += (size_t)nb * sizeof(int);
    int* bucket  = (int*)wsb;                           wsb += (size_t)E * sizeof(int);

    hipMemsetAsync(counts, 0, (size_t)N * sizeof(int), stream);

    gemm_kernel<<<(N + 63) / 64, 256, 0, stream>>>(x, W, xl, N);
    attn_kernel<<<(N + 3) / 4, 256, 0, stream>>>(xl, att_src, att_dst, a_src, a_dst, N);
    hist_kernel<<<(E + 255) / 256, 256, 0, stream>>>(ei, ei + E, counts, E);
    reduce_kernel<<<nb, 256, 0, stream>>>(counts, blockSums, N);
    scan_top_kernel<<<1, 256, 0, stream>>>(blockSums, blockPrefix, nb);
    apply_kernel<<<nb, 256, 0, stream>>>(counts, blockPrefix, offsets, cursor, N);
    scatter_kernel<<<(E + 255) / 256, 256, 0, stream>>>(ei, ei + E, cursor, bucket, E);
    gather_kernel<<<(N + 3) / 4, 256, 0, stream>>>(offsets, counts, bucket, xl, a_src, a_dst, bias, out, N);
}

// Round 4
// 287.947 us; speedup vs baseline: 5.2758x; 1.0697x over previous
//
#include <hip/hip_runtime.h>
#include <math.h>

#define CDIM 128
#define HEADS 4
#define NEG 0.2f

// ---------------- GEMM: xl = x @ W  (N x 128) @ (128 x 128) ----------------
__global__ __launch_bounds__(256) void gemm_kernel(const float* __restrict__ x,
                                                   const float* __restrict__ W,
                                                   float* __restrict__ xl, int N) {
    __shared__ float xs[64][68];
    __shared__ float wsh[64][128];
    const int tid = threadIdx.x;
    const int row0 = blockIdx.x * 64;
    const int tr = tid >> 4;
    const int tc = tid & 15;
    const int cbase = tc * 4;

    float acc[4][8];
#pragma unroll
    for (int r = 0; r < 4; ++r)
#pragma unroll
        for (int j = 0; j < 8; ++j) acc[r][j] = 0.f;

    for (int k0 = 0; k0 < 128; k0 += 64) {
        __syncthreads();
#pragma unroll
        for (int i = 0; i < 4; ++i) {
            int f = tid + i * 256;
            int r = f >> 4, k4 = f & 15;
            float4 v = make_float4(0.f, 0.f, 0.f, 0.f);
            int gr = row0 + r;
            if (gr < N) v = *(const float4*)(x + (size_t)gr * CDIM + k0 + k4 * 4);
            *(float4*)(&xs[r][k4 * 4]) = v;
        }
#pragma unroll
        for (int i = 0; i < 8; ++i) {
            int f = tid + i * 256;
            int kr = f >> 5, c4 = f & 31;
            float4 v = *(const float4*)(W + (size_t)(k0 + kr) * CDIM + c4 * 4);
            *(float4*)(&wsh[kr][c4 * 4]) = v;
        }
        __syncthreads();
#pragma unroll 4
        for (int kk = 0; kk < 64; ++kk) {
            float xv0 = xs[tr * 4 + 0][kk];
            float xv1 = xs[tr * 4 + 1][kk];
            float xv2 = xs[tr * 4 + 2][kk];
            float xv3 = xs[tr * 4 + 3][kk];
            float4 w0 = *(const float4*)(&wsh[kk][cbase]);
            float4 w1 = *(const float4*)(&wsh[kk][cbase + 64]);
            acc[0][0] += xv0 * w0.x; acc[0][1] += xv0 * w0.y; acc[0][2] += xv0 * w0.z; acc[0][3] += xv0 * w0.w;
            acc[0][4] += xv0 * w1.x; acc[0][5] += xv0 * w1.y; acc[0][6] += xv0 * w1.z; acc[0][7] += xv0 * w1.w;
            acc[1][0] += xv1 * w0.x; acc[1][1] += xv1 * w0.y; acc[1][2] += xv1 * w0.z; acc[1][3] += xv1 * w0.w;
            acc[1][4] += xv1 * w1.x; acc[1][5] += xv1 * w1.y; acc[1][6] += xv1 * w1.z; acc[1][7] += xv1 * w1.w;
            acc[2][0] += xv2 * w0.x; acc[2][1] += xv2 * w0.y; acc[2][2] += xv2 * w0.z; acc[2][3] += xv2 * w0.w;
            acc[2][4] += xv2 * w1.x; acc[2][5] += xv2 * w1.y; acc[2][6] += xv2 * w1.z; acc[2][7] += xv2 * w1.w;
            acc[3][0] += xv3 * w0.x; acc[3][1] += xv3 * w0.y; acc[3][2] += xv3 * w0.z; acc[3][3] += xv3 * w0.w;
            acc[3][4] += xv3 * w1.x; acc[3][5] += xv3 * w1.y; acc[3][6] += xv3 * w1.z; acc[3][7] += xv3 * w1.w;
        }
    }
#pragma unroll
    for (int r = 0; r < 4; ++r) {
        int row = row0 + tr * 4 + r;
        if (row < N) {
            *(float4*)(xl + (size_t)row * CDIM + cbase) = make_float4(acc[r][0], acc[r][1], acc[r][2], acc[r][3]);
            *(float4*)(xl + (size_t)row * CDIM + cbase + 64) = make_float4(acc[r][4], acc[r][5], acc[r][6], acc[r][7]);
        }
    }
}

// ---------------- per-node attention logits a_src/a_dst [N,4] ----------------
__global__ __launch_bounds__(256) void attn_kernel(const float* __restrict__ xl,
                                                   const float* __restrict__ att_src,
                                                   const float* __restrict__ att_dst,
                                                   float* __restrict__ a_src,
                                                   float* __restrict__ a_dst, int N) {
    int node = blockIdx.x * 4 + (threadIdx.x >> 6);
    int lane = threadIdx.x & 63;
    if (node >= N) return;
    float v0 = xl[(size_t)node * CDIM + lane];
    float v1 = xl[(size_t)node * CDIM + lane + 64];
    float ps0 = v0 * att_src[lane];
    float ps1 = v1 * att_src[lane + 64];
    float pd0 = v0 * att_dst[lane];
    float pd1 = v1 * att_dst[lane + 64];
#pragma unroll
    for (int off = 16; off > 0; off >>= 1) {
        ps0 += __shfl_down(ps0, off, 32);
        ps1 += __shfl_down(ps1, off, 32);
        pd0 += __shfl_down(pd0, off, 32);
        pd1 += __shfl_down(pd1, off, 32);
    }
    if ((lane & 31) == 0) {
        int h01 = lane >> 5;
        a_src[node * 4 + h01] = ps0;
        a_src[node * 4 + 2 + h01] = ps1;
        a_dst[node * 4 + h01] = pd0;
        a_dst[node * 4 + 2 + h01] = pd1;
    }
}

// ---------------- CSR build: histogram of dst (self loops dropped) ----------------
__global__ __launch_bounds__(256) void hist_kernel(const int* __restrict__ src,
                                                   const int* __restrict__ dst,
                                                   int* __restrict__ counts, int E) {
    int e = blockIdx.x * 256 + threadIdx.x;
    if (e >= E) return;
    int s = src[e], d = dst[e];
    if (s != d) atomicAdd(&counts[d], 1);
}

// ---------------- device-wide exclusive scan (3 phases, 256 elems/block) ----------------
__global__ __launch_bounds__(256) void reduce_kernel(const int* __restrict__ counts,
                                                     int* __restrict__ blockSums, int N) {
    __shared__ int sh[256];
    int idx = blockIdx.x * 256 + threadIdx.x;
    sh[threadIdx.x] = (idx < N) ? counts[idx] : 0;
    __syncthreads();
    for (int off = 128; off > 0; off >>= 1) {
        if (threadIdx.x < off) sh[threadIdx.x] += sh[threadIdx.x + off];
        __syncthreads();
    }
    if (threadIdx.x == 0) blockSums[blockIdx.x] = sh[0];
}

__global__ __launch_bounds__(256) void scan_top_kernel(int* __restrict__ blockSums,
                                                       int* __restrict__ blockPrefix, int nb) {
    __shared__ int sh[256];
    int t = threadIdx.x;
    sh[t] = (t < nb) ? blockSums[t] : 0;
    __syncthreads();
    for (int off = 1; off < 256; off <<= 1) {
        int v = (t >= off) ? sh[t - off] : 0;
        __syncthreads();
        sh[t] += v;
        __syncthreads();
    }
    if (t < nb) blockPrefix[t] = (t == 0) ? 0 : sh[t - 1];
}

__global__ __launch_bounds__(256) void apply_kernel(const int* __restrict__ counts,
                                                    const int* __restrict__ blockPrefix,
                                                    int* __restrict__ offsets,
                                                    int* __restrict__ cursor, int N) {
    __shared__ int sh[256];
    int idx = blockIdx.x * 256 + threadIdx.x;
    int t = threadIdx.x;
    int c = (idx < N) ? counts[idx] : 0;
    sh[t] = c;
    __syncthreads();
    for (int off = 1; off < 256; off <<= 1) {
        int v = (t >= off) ? sh[t - off] : 0;
        __syncthreads();
        sh[t] += v;
        __syncthreads();
    }
    if (idx < N) {
        int excl = sh[t] - c + blockPrefix[blockIdx.x];
        offsets[idx] = excl;
        cursor[idx] = excl;
    }
}

// scatter src ids into destination buckets
__global__ __launch_bounds__(256) void scatter_kernel(const int* __restrict__ src,
                                                      const int* __restrict__ dst,
                                                      int* __restrict__ cursor,
                                                      int* __restrict__ bucket, int E) {
    int e = blockIdx.x * 256 + threadIdx.x;
    if (e >= E) return;
    int s = src[e], d = dst[e];
    if (s == d) return;
    int pos = atomicAdd(&cursor[d], 1);
    bucket[pos] = s;
}

// ---------------- gather: 32 lanes per dst node, float4/lane, 4x unrolled ----------------
__global__ __launch_bounds__(256) void gather_kernel(const int* __restrict__ offsets,
                                                     const int* __restrict__ counts,
                                                     const int* __restrict__ bucket,
                                                     const float* __restrict__ xl,
                                                     const float* __restrict__ a_src,
                                                     const float* __restrict__ a_dst,
                                                     const float* __restrict__ bias,
                                                     float* __restrict__ out, int N) {
    int node = blockIdx.x * 8 + (threadIdx.x >> 5);
    int lane = threadIdx.x & 31;
    if (node >= N) return;
    const int c4 = lane * 4;       // 4 consecutive channels per lane
    const int h = lane >> 3;       // head = channel group / 32
    const float ad = a_dst[node * 4 + h];

    const int beg = offsets[node];
    const int cnt = counts[node];

    float4 acc = make_float4(0.f, 0.f, 0.f, 0.f);
    float den = 0.f;

    int j = 0;
    for (; j + 4 <= cnt; j += 4) {
        // 4 independent index loads
        int s0 = bucket[beg + j + 0];
        int s1 = bucket[beg + j + 1];
        int s2 = bucket[beg + j + 2];
        int s3 = bucket[beg + j + 3];
        // 4 independent logit loads
        float e0 = a_src[s0 * 4 + h] + ad;
        float e1 = a_src[s1 * 4 + h] + ad;
        float e2 = a_src[s2 * 4 + h] + ad;
        float e3 = a_src[s3 * 4 + h] + ad;
        // 4 independent 16B row loads
        float4 x0 = *(const float4*)(xl + (size_t)s0 * CDIM + c4);
        float4 x1 = *(const float4*)(xl + (size_t)s1 * CDIM + c4);
        float4 x2 = *(const float4*)(xl + (size_t)s2 * CDIM + c4);
        float4 x3 = *(const float4*)(xl + (size_t)s3 * CDIM + c4);
        e0 = e0 > 0.f ? e0 : NEG * e0;
        e1 = e1 > 0.f ? e1 : NEG * e1;
        e2 = e2 > 0.f ? e2 : NEG * e2;
        e3 = e3 > 0.f ? e3 : NEG * e3;
        float w0 = __expf(e0), w1 = __expf(e1), w2 = __expf(e2), w3 = __expf(e3);
        acc.x += w0 * x0.x; acc.y += w0 * x0.y; acc.z += w0 * x0.z; acc.w += w0 * x0.w;
        acc.x += w1 * x1.x; acc.y += w1 * x1.y; acc.z += w1 * x1.z; acc.w += w1 * x1.w;
        acc.x += w2 * x2.x; acc.y += w2 * x2.y; acc.z += w2 * x2.z; acc.w += w2 * x2.w;
        acc.x += w3 * x3.x; acc.y += w3 * x3.y; acc.z += w3 * x3.z; acc.w += w3 * x3.w;
        den += w0 + w1 + w2 + w3;
    }
    for (; j < cnt; ++j) {
        int s = bucket[beg + j];
        float e = a_src[s * 4 + h] + ad;
        float4 xv = *(const float4*)(xl + (size_t)s * CDIM + c4);
        e = e > 0.f ? e : NEG * e;
        float w = __expf(e);
        acc.x += w * xv.x; acc.y += w * xv.y; acc.z += w * xv.z; acc.w += w * xv.w;
        den += w;
    }
    // self loop
    float es = a_src[node * 4 + h] + ad;
    es = es > 0.f ? es : NEG * es;
    float ws = __expf(es);
    float4 xv = *(const float4*)(xl + (size_t)node * CDIM + c4);
    acc.x += ws * xv.x; acc.y += ws * xv.y; acc.z += ws * xv.z; acc.w += ws * xv.w;
    den += ws;

    float inv = 1.0f / den;
    float4 b = *(const float4*)(bias + c4);
    float4 o;
    o.x = (acc.x * inv + b.x) * 0.5f;
    o.y = (acc.y * inv + b.y) * 0.5f;
    o.z = (acc.z * inv + b.z) * 0.5f;
    o.w = (acc.w * inv + b.w) * 0.5f;
    *(float4*)(out + (size_t)node * CDIM + c4) = o;
}

extern "C" void kernel_launch(void* const* d_in, const int* in_sizes, int n_in,
                              void* d_out, int out_size, void* d_ws, size_t ws_size,
                              hipStream_t stream) {
    const float* x       = (const float*)d_in[0];
    const int*   ei      = (const int*)d_in[1];
    const float* W       = (const float*)d_in[2];
    const float* att_src = (const float*)d_in[3];
    const float* att_dst = (const float*)d_in[4];
    const float* bias    = (const float*)d_in[5];
    float* out = (float*)d_out;

    const int N = in_sizes[0] / CDIM;
    const int E = in_sizes[1] / 2;
    const int nb = (N + 255) / 256;

    char* wsb = (char*)d_ws;
    float* xl    = (float*)wsb;                         wsb += (size_t)N * CDIM * sizeof(float);
    float* a_src = (float*)wsb;                         wsb += (size_t)N * HEADS * sizeof(float);
    float* a_dst = (float*)wsb;                         wsb += (size_t)N * HEADS * sizeof(float);
    int* counts  = (int*)wsb;                           wsb += (size_t)N * sizeof(int);
    int* offsets = (int*)wsb;                           wsb += (size_t)N * sizeof(int);
    int* cursor  = (int*)wsb;                           wsb += (size_t)N * sizeof(int);
    int* blockSums   = (int*)wsb;                       wsb += (size_t)nb * sizeof(int);
    int* blockPrefix = (int*)wsb;                       wsb += (size_t)nb * sizeof(int);
    int* bucket  = (int*)wsb;                           wsb += (size_t)E * sizeof(int);

    hipMemsetAsync(counts, 0, (size_t)N * sizeof(int), stream);

    gemm_kernel<<<(N + 63) / 64, 256, 0, stream>>>(x, W, xl, N);
    attn_kernel<<<(N + 3) / 4, 256, 0, stream>>>(xl, att_src, att_dst, a_src, a_dst, N);
    hist_kernel<<<(E + 255) / 256, 256, 0, stream>>>(ei, ei + E, counts, E);
    reduce_kernel<<<nb, 256, 0, stream>>>(counts, blockSums, N);
    scan_top_kernel<<<1, 256, 0, stream>>>(blockSums, blockPrefix, nb);
    apply_kernel<<<nb, 256, 0, stream>>>(counts, blockPrefix, offsets, cursor, N);
    scatter_kernel<<<(E + 255) / 256, 256, 0, stream>>>(ei, ei + E, cursor, bucket, E);
    gather_kernel<<<(N + 7) / 8, 256, 0, stream>>>(offsets, counts, bucket, xl, a_src, a_dst, bias, out, N);
}

// Round 5
// 257.799 us; speedup vs baseline: 5.8928x; 1.1169x over previous
//
#include <hip/hip_runtime.h>
#include <math.h>

#define CDIM 128
#define HEADS 4
#define NEG 0.2f

static __device__ __forceinline__ unsigned short f2bf(float f) {
    unsigned u = __float_as_uint(f);
    u += 0x7FFFu + ((u >> 16) & 1u);   // round-to-nearest-even
    return (unsigned short)(u >> 16);
}
static __device__ __forceinline__ float bf2f(unsigned short s) {
    return __uint_as_float((unsigned)s << 16);
}

// ---------------- GEMM: xl = x @ W, 128x128 tile, 8x8 per thread ----------------
// also emits bf16 copy xlh for the gather phase
__global__ __launch_bounds__(256) void gemm_kernel(const float* __restrict__ x,
                                                   const float* __restrict__ W,
                                                   float* __restrict__ xl,
                                                   unsigned short* __restrict__ xlh, int N) {
    __shared__ float xs[128][68];    // 128 rows x 64 k, stride 68 (272B, 16B-aligned)
    __shared__ float wsh[64][128];   // 64 k x 128 cols
    const int tid = threadIdx.x;
    const int row0 = blockIdx.x * 128;
    const int tr = tid >> 4;         // 0..15 -> rows tr*8..tr*8+7
    const int tc = tid & 15;         // cols tc*4..+3 and +64
    const int cbase = tc * 4;

    float acc[8][8];
#pragma unroll
    for (int r = 0; r < 8; ++r)
#pragma unroll
        for (int j = 0; j < 8; ++j) acc[r][j] = 0.f;

    for (int k0 = 0; k0 < 128; k0 += 64) {
        __syncthreads();
        // stage x tile: 128 rows x 64 k = 2048 float4, 8/thread
#pragma unroll
        for (int i = 0; i < 8; ++i) {
            int f = tid + i * 256;
            int r = f >> 4, k4 = f & 15;
            float4 v = make_float4(0.f, 0.f, 0.f, 0.f);
            int gr = row0 + r;
            if (gr < N) v = *(const float4*)(x + (size_t)gr * CDIM + k0 + k4 * 4);
            *(float4*)(&xs[r][k4 * 4]) = v;
        }
        // stage W tile: 64 k x 128 cols = 2048 float4, 8/thread
#pragma unroll
        for (int i = 0; i < 8; ++i) {
            int f = tid + i * 256;
            int kr = f >> 5, c4 = f & 31;
            float4 v = *(const float4*)(W + (size_t)(k0 + kr) * CDIM + c4 * 4);
            *(float4*)(&wsh[kr][c4 * 4]) = v;
        }
        __syncthreads();
        for (int kk = 0; kk < 64; kk += 4) {
            float4 xv[8];
#pragma unroll
            for (int r = 0; r < 8; ++r) xv[r] = *(const float4*)(&xs[tr * 8 + r][kk]);
#pragma unroll
            for (int q = 0; q < 4; ++q) {
                float4 w0 = *(const float4*)(&wsh[kk + q][cbase]);
                float4 w1 = *(const float4*)(&wsh[kk + q][cbase + 64]);
#pragma unroll
                for (int r = 0; r < 8; ++r) {
                    float xr = ((const float*)&xv[r])[q];
                    acc[r][0] += xr * w0.x; acc[r][1] += xr * w0.y;
                    acc[r][2] += xr * w0.z; acc[r][3] += xr * w0.w;
                    acc[r][4] += xr * w1.x; acc[r][5] += xr * w1.y;
                    acc[r][6] += xr * w1.z; acc[r][7] += xr * w1.w;
                }
            }
        }
    }
#pragma unroll
    for (int r = 0; r < 8; ++r) {
        int row = row0 + tr * 8 + r;
        if (row < N) {
            *(float4*)(xl + (size_t)row * CDIM + cbase) = make_float4(acc[r][0], acc[r][1], acc[r][2], acc[r][3]);
            *(float4*)(xl + (size_t)row * CDIM + cbase + 64) = make_float4(acc[r][4], acc[r][5], acc[r][6], acc[r][7]);
            ushort4 h0, h1;
            h0.x = f2bf(acc[r][0]); h0.y = f2bf(acc[r][1]); h0.z = f2bf(acc[r][2]); h0.w = f2bf(acc[r][3]);
            h1.x = f2bf(acc[r][4]); h1.y = f2bf(acc[r][5]); h1.z = f2bf(acc[r][6]); h1.w = f2bf(acc[r][7]);
            *(ushort4*)(xlh + (size_t)row * CDIM + cbase) = h0;
            *(ushort4*)(xlh + (size_t)row * CDIM + cbase + 64) = h1;
        }
    }
}

// ---------------- per-node attention logits a_src/a_dst [N,4] (fp32 xl) ----------------
__global__ __launch_bounds__(256) void attn_kernel(const float* __restrict__ xl,
                                                   const float* __restrict__ att_src,
                                                   const float* __restrict__ att_dst,
                                                   float* __restrict__ a_src,
                                                   float* __restrict__ a_dst, int N) {
    int node = blockIdx.x * 4 + (threadIdx.x >> 6);
    int lane = threadIdx.x & 63;
    if (node >= N) return;
    float v0 = xl[(size_t)node * CDIM + lane];
    float v1 = xl[(size_t)node * CDIM + lane + 64];
    float ps0 = v0 * att_src[lane];
    float ps1 = v1 * att_src[lane + 64];
    float pd0 = v0 * att_dst[lane];
    float pd1 = v1 * att_dst[lane + 64];
#pragma unroll
    for (int off = 16; off > 0; off >>= 1) {
        ps0 += __shfl_down(ps0, off, 32);
        ps1 += __shfl_down(ps1, off, 32);
        pd0 += __shfl_down(pd0, off, 32);
        pd1 += __shfl_down(pd1, off, 32);
    }
    if ((lane & 31) == 0) {
        int h01 = lane >> 5;
        a_src[node * 4 + h01] = ps0;
        a_src[node * 4 + 2 + h01] = ps1;
        a_dst[node * 4 + h01] = pd0;
        a_dst[node * 4 + 2 + h01] = pd1;
    }
}

// ---------------- CSR build ----------------
__global__ __launch_bounds__(256) void hist_kernel(const int* __restrict__ src,
                                                   const int* __restrict__ dst,
                                                   int* __restrict__ counts, int E) {
    int e = blockIdx.x * 256 + threadIdx.x;
    if (e >= E) return;
    int s = src[e], d = dst[e];
    if (s != d) atomicAdd(&counts[d], 1);
}

__global__ __launch_bounds__(256) void reduce_kernel(const int* __restrict__ counts,
                                                     int* __restrict__ blockSums, int N) {
    __shared__ int sh[256];
    int idx = blockIdx.x * 256 + threadIdx.x;
    sh[threadIdx.x] = (idx < N) ? counts[idx] : 0;
    __syncthreads();
    for (int off = 128; off > 0; off >>= 1) {
        if (threadIdx.x < off) sh[threadIdx.x] += sh[threadIdx.x + off];
        __syncthreads();
    }
    if (threadIdx.x == 0) blockSums[blockIdx.x] = sh[0];
}

__global__ __launch_bounds__(256) void scan_top_kernel(int* __restrict__ blockSums,
                                                       int* __restrict__ blockPrefix, int nb) {
    __shared__ int sh[256];
    int t = threadIdx.x;
    sh[t] = (t < nb) ? blockSums[t] : 0;
    __syncthreads();
    for (int off = 1; off < 256; off <<= 1) {
        int v = (t >= off) ? sh[t - off] : 0;
        __syncthreads();
        sh[t] += v;
        __syncthreads();
    }
    if (t < nb) blockPrefix[t] = (t == 0) ? 0 : sh[t - 1];
}

__global__ __launch_bounds__(256) void apply_kernel(const int* __restrict__ counts,
                                                    const int* __restrict__ blockPrefix,
                                                    int* __restrict__ offsets,
                                                    int* __restrict__ cursor, int N) {
    __shared__ int sh[256];
    int idx = blockIdx.x * 256 + threadIdx.x;
    int t = threadIdx.x;
    int c = (idx < N) ? counts[idx] : 0;
    sh[t] = c;
    __syncthreads();
    for (int off = 1; off < 256; off <<= 1) {
        int v = (t >= off) ? sh[t - off] : 0;
        __syncthreads();
        sh[t] += v;
        __syncthreads();
    }
    if (idx < N) {
        int excl = sh[t] - c + blockPrefix[blockIdx.x];
        offsets[idx] = excl;
        cursor[idx] = excl;
    }
}

__global__ __launch_bounds__(256) void scatter_kernel(const int* __restrict__ src,
                                                      const int* __restrict__ dst,
                                                      int* __restrict__ cursor,
                                                      int* __restrict__ bucket, int E) {
    int e = blockIdx.x * 256 + threadIdx.x;
    if (e >= E) return;
    int s = src[e], d = dst[e];
    if (s == d) return;
    int pos = atomicAdd(&cursor[d], 1);
    bucket[pos] = s;
}

// ---------------- gather: 32 lanes/node, bf16 messages, 4x unrolled ----------------
__global__ __launch_bounds__(256) void gather_kernel(const int* __restrict__ offsets,
                                                     const int* __restrict__ counts,
                                                     const int* __restrict__ bucket,
                                                     const unsigned short* __restrict__ xlh,
                                                     const float* __restrict__ a_src,
                                                     const float* __restrict__ a_dst,
                                                     const float* __restrict__ bias,
                                                     float* __restrict__ out, int N) {
    int node = blockIdx.x * 8 + (threadIdx.x >> 5);
    int lane = threadIdx.x & 31;
    if (node >= N) return;
    const int c4 = lane * 4;
    const int h = lane >> 3;
    const float ad = a_dst[node * 4 + h];

    const int beg = offsets[node];
    const int cnt = counts[node];

    float4 acc = make_float4(0.f, 0.f, 0.f, 0.f);
    float den = 0.f;

    int j = 0;
    for (; j + 4 <= cnt; j += 4) {
        int s0 = bucket[beg + j + 0];
        int s1 = bucket[beg + j + 1];
        int s2 = bucket[beg + j + 2];
        int s3 = bucket[beg + j + 3];
        float e0 = a_src[s0 * 4 + h] + ad;
        float e1 = a_src[s1 * 4 + h] + ad;
        float e2 = a_src[s2 * 4 + h] + ad;
        float e3 = a_src[s3 * 4 + h] + ad;
        ushort4 u0 = *(const ushort4*)(xlh + (size_t)s0 * CDIM + c4);
        ushort4 u1 = *(const ushort4*)(xlh + (size_t)s1 * CDIM + c4);
        ushort4 u2 = *(const ushort4*)(xlh + (size_t)s2 * CDIM + c4);
        ushort4 u3 = *(const ushort4*)(xlh + (size_t)s3 * CDIM + c4);
        e0 = e0 > 0.f ? e0 : NEG * e0;
        e1 = e1 > 0.f ? e1 : NEG * e1;
        e2 = e2 > 0.f ? e2 : NEG * e2;
        e3 = e3 > 0.f ? e3 : NEG * e3;
        float w0 = __expf(e0), w1 = __expf(e1), w2 = __expf(e2), w3 = __expf(e3);
        acc.x += w0 * bf2f(u0.x); acc.y += w0 * bf2f(u0.y); acc.z += w0 * bf2f(u0.z); acc.w += w0 * bf2f(u0.w);
        acc.x += w1 * bf2f(u1.x); acc.y += w1 * bf2f(u1.y); acc.z += w1 * bf2f(u1.z); acc.w += w1 * bf2f(u1.w);
        acc.x += w2 * bf2f(u2.x); acc.y += w2 * bf2f(u2.y); acc.z += w2 * bf2f(u2.z); acc.w += w2 * bf2f(u2.w);
        acc.x += w3 * bf2f(u3.x); acc.y += w3 * bf2f(u3.y); acc.z += w3 * bf2f(u3.z); acc.w += w3 * bf2f(u3.w);
        den += w0 + w1 + w2 + w3;
    }
    for (; j < cnt; ++j) {
        int s = bucket[beg + j];
        float e = a_src[s * 4 + h] + ad;
        ushort4 u = *(const ushort4*)(xlh + (size_t)s * CDIM + c4);
        e = e > 0.f ? e : NEG * e;
        float w = __expf(e);
        acc.x += w * bf2f(u.x); acc.y += w * bf2f(u.y); acc.z += w * bf2f(u.z); acc.w += w * bf2f(u.w);
        den += w;
    }
    // self loop
    float es = a_src[node * 4 + h] + ad;
    es = es > 0.f ? es : NEG * es;
    float ws = __expf(es);
    ushort4 u = *(const ushort4*)(xlh + (size_t)node * CDIM + c4);
    acc.x += ws * bf2f(u.x); acc.y += ws * bf2f(u.y); acc.z += ws * bf2f(u.z); acc.w += ws * bf2f(u.w);
    den += ws;

    float inv = 1.0f / den;
    float4 b = *(const float4*)(bias + c4);
    float4 o;
    o.x = (acc.x * inv + b.x) * 0.5f;
    o.y = (acc.y * inv + b.y) * 0.5f;
    o.z = (acc.z * inv + b.z) * 0.5f;
    o.w = (acc.w * inv + b.w) * 0.5f;
    *(float4*)(out + (size_t)node * CDIM + c4) = o;
}

extern "C" void kernel_launch(void* const* d_in, const int* in_sizes, int n_in,
                              void* d_out, int out_size, void* d_ws, size_t ws_size,
                              hipStream_t stream) {
    const float* x       = (const float*)d_in[0];
    const int*   ei      = (const int*)d_in[1];
    const float* W       = (const float*)d_in[2];
    const float* att_src = (const float*)d_in[3];
    const float* att_dst = (const float*)d_in[4];
    const float* bias    = (const float*)d_in[5];
    float* out = (float*)d_out;

    const int N = in_sizes[0] / CDIM;
    const int E = in_sizes[1] / 2;
    const int nb = (N + 255) / 256;

    char* wsb = (char*)d_ws;
    float* xl    = (float*)wsb;                         wsb += (size_t)N * CDIM * sizeof(float);
    unsigned short* xlh = (unsigned short*)wsb;         wsb += (size_t)N * CDIM * sizeof(unsigned short);
    float* a_src = (float*)wsb;                         wsb += (size_t)N * HEADS * sizeof(float);
    float* a_dst = (float*)wsb;                         wsb += (size_t)N * HEADS * sizeof(float);
    int* counts  = (int*)wsb;                           wsb += (size_t)N * sizeof(int);
    int* offsets = (int*)wsb;                           wsb += (size_t)N * sizeof(int);
    int* cursor  = (int*)wsb;                           wsb += (size_t)N * sizeof(int);
    int* blockSums   = (int*)wsb;                       wsb += (size_t)nb * sizeof(int);
    int* blockPrefix = (int*)wsb;                       wsb += (size_t)nb * sizeof(int);
    int* bucket  = (int*)wsb;                           wsb += (size_t)E * sizeof(int);

    hipMemsetAsync(counts, 0, (size_t)N * sizeof(int), stream);

    gemm_kernel<<<(N + 127) / 128, 256, 0, stream>>>(x, W, xl, xlh, N);
    attn_kernel<<<(N + 3) / 4, 256, 0, stream>>>(xl, att_src, att_dst, a_src, a_dst, N);
    hist_kernel<<<(E + 255) / 256, 256, 0, stream>>>(ei, ei + E, counts, E);
    reduce_kernel<<<nb, 256, 0, stream>>>(counts, blockSums, N);
    scan_top_kernel<<<1, 256, 0, stream>>>(blockSums, blockPrefix, nb);
    apply_kernel<<<nb, 256, 0, stream>>>(counts, blockPrefix, offsets, cursor, N);
    scatter_kernel<<<(E + 255) / 256, 256, 0, stream>>>(ei, ei + E, cursor, bucket, E);
    gather_kernel<<<(N + 7) / 8, 256, 0, stream>>>(offsets, counts, bucket, xlh, a_src, a_dst, bias, out, N);
}

// Round 6
// 216.905 us; speedup vs baseline: 7.0038x; 1.1885x over previous
//
#include <hip/hip_runtime.h>
#include <math.h>

#define CDIM 128
#define HEADS 4
#define NEG 0.2f

static __device__ __forceinline__ unsigned short f2bf(float f) {
    unsigned u = __float_as_uint(f);
    u += 0x7FFFu + ((u >> 16) & 1u);   // round-to-nearest-even
    return (unsigned short)(u >> 16);
}
static __device__ __forceinline__ float bf2f(unsigned short s) {
    return __uint_as_float((unsigned)s << 16);
}

// ---------------- GEMM: xl = x @ W, 128x128 tile, 8x8 per thread ----------------
__global__ __launch_bounds__(256) void gemm_kernel(const float* __restrict__ x,
                                                   const float* __restrict__ W,
                                                   float* __restrict__ xl,
                                                   unsigned short* __restrict__ xlh, int N) {
    __shared__ float xs[128][68];
    __shared__ float wsh[64][128];
    const int tid = threadIdx.x;
    const int row0 = blockIdx.x * 128;
    const int tr = tid >> 4;
    const int tc = tid & 15;
    const int cbase = tc * 4;

    float acc[8][8];
#pragma unroll
    for (int r = 0; r < 8; ++r)
#pragma unroll
        for (int j = 0; j < 8; ++j) acc[r][j] = 0.f;

    for (int k0 = 0; k0 < 128; k0 += 64) {
        __syncthreads();
#pragma unroll
        for (int i = 0; i < 8; ++i) {
            int f = tid + i * 256;
            int r = f >> 4, k4 = f & 15;
            float4 v = make_float4(0.f, 0.f, 0.f, 0.f);
            int gr = row0 + r;
            if (gr < N) v = *(const float4*)(x + (size_t)gr * CDIM + k0 + k4 * 4);
            *(float4*)(&xs[r][k4 * 4]) = v;
        }
#pragma unroll
        for (int i = 0; i < 8; ++i) {
            int f = tid + i * 256;
            int kr = f >> 5, c4 = f & 31;
            float4 v = *(const float4*)(W + (size_t)(k0 + kr) * CDIM + c4 * 4);
            *(float4*)(&wsh[kr][c4 * 4]) = v;
        }
        __syncthreads();
        for (int kk = 0; kk < 64; kk += 4) {
            float4 xv[8];
#pragma unroll
            for (int r = 0; r < 8; ++r) xv[r] = *(const float4*)(&xs[tr * 8 + r][kk]);
#pragma unroll
            for (int q = 0; q < 4; ++q) {
                float4 w0 = *(const float4*)(&wsh[kk + q][cbase]);
                float4 w1 = *(const float4*)(&wsh[kk + q][cbase + 64]);
#pragma unroll
                for (int r = 0; r < 8; ++r) {
                    float xr = ((const float*)&xv[r])[q];
                    acc[r][0] += xr * w0.x; acc[r][1] += xr * w0.y;
                    acc[r][2] += xr * w0.z; acc[r][3] += xr * w0.w;
                    acc[r][4] += xr * w1.x; acc[r][5] += xr * w1.y;
                    acc[r][6] += xr * w1.z; acc[r][7] += xr * w1.w;
                }
            }
        }
    }
#pragma unroll
    for (int r = 0; r < 8; ++r) {
        int row = row0 + tr * 8 + r;
        if (row < N) {
            *(float4*)(xl + (size_t)row * CDIM + cbase) = make_float4(acc[r][0], acc[r][1], acc[r][2], acc[r][3]);
            *(float4*)(xl + (size_t)row * CDIM + cbase + 64) = make_float4(acc[r][4], acc[r][5], acc[r][6], acc[r][7]);
            ushort4 h0, h1;
            h0.x = f2bf(acc[r][0]); h0.y = f2bf(acc[r][1]); h0.z = f2bf(acc[r][2]); h0.w = f2bf(acc[r][3]);
            h1.x = f2bf(acc[r][4]); h1.y = f2bf(acc[r][5]); h1.z = f2bf(acc[r][6]); h1.w = f2bf(acc[r][7]);
            *(ushort4*)(xlh + (size_t)row * CDIM + cbase) = h0;
            *(ushort4*)(xlh + (size_t)row * CDIM + cbase + 64) = h1;
        }
    }
}

// ---------------- per-node attention logits a_src/a_dst [N,4] (fp32 xl) ----------------
__global__ __launch_bounds__(256) void attn_kernel(const float* __restrict__ xl,
                                                   const float* __restrict__ att_src,
                                                   const float* __restrict__ att_dst,
                                                   float* __restrict__ a_src,
                                                   float* __restrict__ a_dst, int N) {
    int node = blockIdx.x * 4 + (threadIdx.x >> 6);
    int lane = threadIdx.x & 63;
    if (node >= N) return;
    float v0 = xl[(size_t)node * CDIM + lane];
    float v1 = xl[(size_t)node * CDIM + lane + 64];
    float ps0 = v0 * att_src[lane];
    float ps1 = v1 * att_src[lane + 64];
    float pd0 = v0 * att_dst[lane];
    float pd1 = v1 * att_dst[lane + 64];
#pragma unroll
    for (int off = 16; off > 0; off >>= 1) {
        ps0 += __shfl_down(ps0, off, 32);
        ps1 += __shfl_down(ps1, off, 32);
        pd0 += __shfl_down(pd0, off, 32);
        pd1 += __shfl_down(pd1, off, 32);
    }
    if ((lane & 31) == 0) {
        int h01 = lane >> 5;
        a_src[node * 4 + h01] = ps0;
        a_src[node * 4 + 2 + h01] = ps1;
        a_dst[node * 4 + h01] = pd0;
        a_dst[node * 4 + 2 + h01] = pd1;
    }
}

// ---------------- CSR build: histogram + per-edge rank ----------------
__global__ __launch_bounds__(256) void hist_kernel(const int* __restrict__ src,
                                                   const int* __restrict__ dst,
                                                   int* __restrict__ counts,
                                                   int* __restrict__ rank, int E) {
    int e = blockIdx.x * 256 + threadIdx.x;
    if (e >= E) return;
    int s = src[e], d = dst[e];
    if (s != d) rank[e] = atomicAdd(&counts[d], 1);
}

__global__ __launch_bounds__(256) void reduce_kernel(const int* __restrict__ counts,
                                                     int* __restrict__ blockSums, int N) {
    __shared__ int sh[256];
    int idx = blockIdx.x * 256 + threadIdx.x;
    sh[threadIdx.x] = (idx < N) ? counts[idx] : 0;
    __syncthreads();
    for (int off = 128; off > 0; off >>= 1) {
        if (threadIdx.x < off) sh[threadIdx.x] += sh[threadIdx.x + off];
        __syncthreads();
    }
    if (threadIdx.x == 0) blockSums[blockIdx.x] = sh[0];
}

__global__ __launch_bounds__(256) void scan_top_kernel(int* __restrict__ blockSums,
                                                       int* __restrict__ blockPrefix, int nb) {
    __shared__ int sh[256];
    int t = threadIdx.x;
    sh[t] = (t < nb) ? blockSums[t] : 0;
    __syncthreads();
    for (int off = 1; off < 256; off <<= 1) {
        int v = (t >= off) ? sh[t - off] : 0;
        __syncthreads();
        sh[t] += v;
        __syncthreads();
    }
    if (t < nb) blockPrefix[t] = (t == 0) ? 0 : sh[t - 1];
}

__global__ __launch_bounds__(256) void apply_kernel(const int* __restrict__ counts,
                                                    const int* __restrict__ blockPrefix,
                                                    int* __restrict__ offsets, int N) {
    __shared__ int sh[256];
    int idx = blockIdx.x * 256 + threadIdx.x;
    int t = threadIdx.x;
    int c = (idx < N) ? counts[idx] : 0;
    sh[t] = c;
    __syncthreads();
    for (int off = 1; off < 256; off <<= 1) {
        int v = (t >= off) ? sh[t - off] : 0;
        __syncthreads();
        sh[t] += v;
        __syncthreads();
    }
    if (idx < N) offsets[idx] = sh[t] - c + blockPrefix[blockIdx.x];
}

// pure scatter: no atomics, slot = offsets[d] + rank[e]
__global__ __launch_bounds__(256) void scatter_kernel(const int* __restrict__ src,
                                                      const int* __restrict__ dst,
                                                      const int* __restrict__ offsets,
                                                      const int* __restrict__ rank,
                                                      int* __restrict__ bucket, int E) {
    int e = blockIdx.x * 256 + threadIdx.x;
    if (e >= E) return;
    int s = src[e], d = dst[e];
    if (s == d) return;
    bucket[offsets[d] + rank[e]] = s;
}

// ---------------- gather: 32 lanes/node, bf16 messages, 4x unrolled ----------------
__global__ __launch_bounds__(256) void gather_kernel(const int* __restrict__ offsets,
                                                     const int* __restrict__ counts,
                                                     const int* __restrict__ bucket,
                                                     const unsigned short* __restrict__ xlh,
                                                     const float* __restrict__ a_src,
                                                     const float* __restrict__ a_dst,
                                                     const float* __restrict__ bias,
                                                     float* __restrict__ out, int N) {
    int node = blockIdx.x * 8 + (threadIdx.x >> 5);
    int lane = threadIdx.x & 31;
    if (node >= N) return;
    const int c4 = lane * 4;
    const int h = lane >> 3;
    const float ad = a_dst[node * 4 + h];

    const int beg = offsets[node];
    const int cnt = counts[node];

    float4 acc = make_float4(0.f, 0.f, 0.f, 0.f);
    float den = 0.f;

    int j = 0;
    for (; j + 4 <= cnt; j += 4) {
        int s0 = bucket[beg + j + 0];
        int s1 = bucket[beg + j + 1];
        int s2 = bucket[beg + j + 2];
        int s3 = bucket[beg + j + 3];
        float e0 = a_src[s0 * 4 + h] + ad;
        float e1 = a_src[s1 * 4 + h] + ad;
        float e2 = a_src[s2 * 4 + h] + ad;
        float e3 = a_src[s3 * 4 + h] + ad;
        ushort4 u0 = *(const ushort4*)(xlh + (size_t)s0 * CDIM + c4);
        ushort4 u1 = *(const ushort4*)(xlh + (size_t)s1 * CDIM + c4);
        ushort4 u2 = *(const ushort4*)(xlh + (size_t)s2 * CDIM + c4);
        ushort4 u3 = *(const ushort4*)(xlh + (size_t)s3 * CDIM + c4);
        e0 = e0 > 0.f ? e0 : NEG * e0;
        e1 = e1 > 0.f ? e1 : NEG * e1;
        e2 = e2 > 0.f ? e2 : NEG * e2;
        e3 = e3 > 0.f ? e3 : NEG * e3;
        float w0 = __expf(e0), w1 = __expf(e1), w2 = __expf(e2), w3 = __expf(e3);
        acc.x += w0 * bf2f(u0.x); acc.y += w0 * bf2f(u0.y); acc.z += w0 * bf2f(u0.z); acc.w += w0 * bf2f(u0.w);
        acc.x += w1 * bf2f(u1.x); acc.y += w1 * bf2f(u1.y); acc.z += w1 * bf2f(u1.z); acc.w += w1 * bf2f(u1.w);
        acc.x += w2 * bf2f(u2.x); acc.y += w2 * bf2f(u2.y); acc.z += w2 * bf2f(u2.z); acc.w += w2 * bf2f(u2.w);
        acc.x += w3 * bf2f(u3.x); acc.y += w3 * bf2f(u3.y); acc.z += w3 * bf2f(u3.z); acc.w += w3 * bf2f(u3.w);
        den += w0 + w1 + w2 + w3;
    }
    for (; j < cnt; ++j) {
        int s = bucket[beg + j];
        float e = a_src[s * 4 + h] + ad;
        ushort4 u = *(const ushort4*)(xlh + (size_t)s * CDIM + c4);
        e = e > 0.f ? e : NEG * e;
        float w = __expf(e);
        acc.x += w * bf2f(u.x); acc.y += w * bf2f(u.y); acc.z += w * bf2f(u.z); acc.w += w * bf2f(u.w);
        den += w;
    }
    // self loop
    float es = a_src[node * 4 + h] + ad;
    es = es > 0.f ? es : NEG * es;
    float ws = __expf(es);
    ushort4 u = *(const ushort4*)(xlh + (size_t)node * CDIM + c4);
    acc.x += ws * bf2f(u.x); acc.y += ws * bf2f(u.y); acc.z += ws * bf2f(u.z); acc.w += ws * bf2f(u.w);
    den += ws;

    float inv = 1.0f / den;
    float4 b = *(const float4*)(bias + c4);
    float4 o;
    o.x = (acc.x * inv + b.x) * 0.5f;
    o.y = (acc.y * inv + b.y) * 0.5f;
    o.z = (acc.z * inv + b.z) * 0.5f;
    o.w = (acc.w * inv + b.w) * 0.5f;
    *(float4*)(out + (size_t)node * CDIM + c4) = o;
}

extern "C" void kernel_launch(void* const* d_in, const int* in_sizes, int n_in,
                              void* d_out, int out_size, void* d_ws, size_t ws_size,
                              hipStream_t stream) {
    const float* x       = (const float*)d_in[0];
    const int*   ei      = (const int*)d_in[1];
    const float* W       = (const float*)d_in[2];
    const float* att_src = (const float*)d_in[3];
    const float* att_dst = (const float*)d_in[4];
    const float* bias    = (const float*)d_in[5];
    float* out = (float*)d_out;

    const int N = in_sizes[0] / CDIM;
    const int E = in_sizes[1] / 2;
    const int nb = (N + 255) / 256;

    char* wsb = (char*)d_ws;
    float* xl    = (float*)wsb;                         wsb += (size_t)N * CDIM * sizeof(float);
    unsigned short* xlh = (unsigned short*)wsb;         wsb += (size_t)N * CDIM * sizeof(unsigned short);
    float* a_src = (float*)wsb;                         wsb += (size_t)N * HEADS * sizeof(float);
    float* a_dst = (float*)wsb;                         wsb += (size_t)N * HEADS * sizeof(float);
    int* counts  = (int*)wsb;                           wsb += (size_t)N * sizeof(int);
    int* offsets = (int*)wsb;                           wsb += (size_t)N * sizeof(int);
    int* blockSums   = (int*)wsb;                       wsb += (size_t)nb * sizeof(int);
    int* blockPrefix = (int*)wsb;                       wsb += (size_t)nb * sizeof(int);
    int* rank    = (int*)wsb;                           wsb += (size_t)E * sizeof(int);
    int* bucket  = (int*)wsb;                           wsb += (size_t)E * sizeof(int);

    hipMemsetAsync(counts, 0, (size_t)N * sizeof(int), stream);

    gemm_kernel<<<(N + 127) / 128, 256, 0, stream>>>(x, W, xl, xlh, N);
    attn_kernel<<<(N + 3) / 4, 256, 0, stream>>>(xl, att_src, att_dst, a_src, a_dst, N);
    hist_kernel<<<(E + 255) / 256, 256, 0, stream>>>(ei, ei + E, counts, rank, E);
    reduce_kernel<<<nb, 256, 0, stream>>>(counts, blockSums, N);
    scan_top_kernel<<<1, 256, 0, stream>>>(blockSums, blockPrefix, nb);
    apply_kernel<<<nb, 256, 0, stream>>>(counts, blockPrefix, offsets, N);
    scatter_kernel<<<(E + 255) / 256, 256, 0, stream>>>(ei, ei + E, offsets, rank, bucket, E);
    gather_kernel<<<(N + 7) / 8, 256, 0, stream>>>(offsets, counts, bucket, xlh, a_src, a_dst, bias, out, N);
}

// Round 7
// 204.181 us; speedup vs baseline: 7.4402x; 1.0623x over previous
//
#include <hip/hip_runtime.h>
#include <math.h>

#define CDIM 128
#define HEADS 4
#define NEG 0.2f

typedef __attribute__((ext_vector_type(8))) short bf16x8;
typedef __attribute__((ext_vector_type(4))) float f32x4;

static __device__ __forceinline__ unsigned short f2bf(float f) {
    unsigned u = __float_as_uint(f);
    u += 0x7FFFu + ((u >> 16) & 1u);   // round-to-nearest-even
    return (unsigned short)(u >> 16);
}
static __device__ __forceinline__ float bf2f(unsigned short s) {
    return __uint_as_float((unsigned)s << 16);
}

#define LDS_STRIDE 136   // 128 + 8 bf16 pad: breaks power-of-2 bank stride

// ---------------- MFMA GEMM + fused attention logits + bf16 output ----------------
// block = 256 (4 waves), 64 rows/block, full K=128 staged once.
// A (x rows) bf16 in LDS row-major; B = W^T bf16 in LDS (Bs[n][k]).
// Per wave: 16 rows x 128 cols = 8 tiles of 16x16, 4 MFMA k-steps each.
// Epilogue: xlh = bf16(xl); a_src/a_dst per-head logits from fp32 accumulators.
__global__ __launch_bounds__(256) void gemm_mfma_kernel(const float* __restrict__ x,
                                                        const float* __restrict__ W,
                                                        const float* __restrict__ att_src,
                                                        const float* __restrict__ att_dst,
                                                        unsigned short* __restrict__ xlh,
                                                        float* __restrict__ a_src,
                                                        float* __restrict__ a_dst, int N) {
    __shared__ unsigned short As[64 * LDS_STRIDE];    // 17.4 KB
    __shared__ unsigned short Bs[128 * LDS_STRIDE];   // 34.8 KB
    const int tid = threadIdx.x;
    const int row0 = blockIdx.x * 64;

    // stage A: 64 rows x 128 k, fp32->bf16, coalesced float4 reads
#pragma unroll
    for (int i = 0; i < 8; ++i) {
        int f = tid + i * 256;
        int r = f >> 5, k4 = f & 31;
        float4 v = make_float4(0.f, 0.f, 0.f, 0.f);
        int gr = row0 + r;
        if (gr < N) v = *(const float4*)(x + (size_t)gr * CDIM + k4 * 4);
        ushort4 h;
        h.x = f2bf(v.x); h.y = f2bf(v.y); h.z = f2bf(v.z); h.w = f2bf(v.w);
        *(ushort4*)(&As[r * LDS_STRIDE + k4 * 4]) = h;
    }
    // stage B = W^T: coalesced float4 reads of W[k][c..c+3], scalar bf16 scatter to Bs[c][k]
#pragma unroll
    for (int i = 0; i < 16; ++i) {
        int f = tid + i * 256;
        int k = f >> 5, c4 = (f & 31) * 4;
        float4 v = *(const float4*)(W + (size_t)k * CDIM + c4);
        Bs[(c4 + 0) * LDS_STRIDE + k] = f2bf(v.x);
        Bs[(c4 + 1) * LDS_STRIDE + k] = f2bf(v.y);
        Bs[(c4 + 2) * LDS_STRIDE + k] = f2bf(v.z);
        Bs[(c4 + 3) * LDS_STRIDE + k] = f2bf(v.w);
    }
    __syncthreads();

    const int wave = tid >> 6;
    const int lane = tid & 63;
    const int m    = lane & 15;    // A row within tile / C col within tile
    const int quad = lane >> 4;    // 0..3
    const int wrow = wave * 16;    // wave's row base within block

    // A fragments: A[m][k = ks*32 + quad*8 + j], one b128 per k-step
    bf16x8 a[4];
#pragma unroll
    for (int ks = 0; ks < 4; ++ks)
        a[ks] = *(const bf16x8*)(&As[(wrow + m) * LDS_STRIDE + ks * 32 + quad * 8]);

    // 8 column tiles of 16: acc[t] holds D rows quad*4+reg, col t*16+m
    f32x4 acc[8];
#pragma unroll
    for (int t = 0; t < 8; ++t) {
        f32x4 c = {0.f, 0.f, 0.f, 0.f};
#pragma unroll
        for (int ks = 0; ks < 4; ++ks) {
            bf16x8 b = *(const bf16x8*)(&Bs[(t * 16 + m) * LDS_STRIDE + ks * 32 + quad * 8]);
            c = __builtin_amdgcn_mfma_f32_16x16x32_bf16(a[ks], b, c, 0, 0, 0);
        }
        acc[t] = c;
    }

    // ---- fused epilogue 1: bf16 xlh store ----
#pragma unroll
    for (int t = 0; t < 8; ++t) {
#pragma unroll
        for (int reg = 0; reg < 4; ++reg) {
            int row = row0 + wrow + quad * 4 + reg;
            if (row < N) xlh[(size_t)row * CDIM + t * 16 + m] = f2bf(acc[t][reg]);
        }
    }

    // ---- fused epilogue 2: per-head attention logits from fp32 acc ----
    // head of col t*16+m is t>>1 (32 cols per head, 2 tiles per head)
    float ps[4][4], pd[4][4];
#pragma unroll
    for (int h = 0; h < 4; ++h)
#pragma unroll
        for (int reg = 0; reg < 4; ++reg) { ps[h][reg] = 0.f; pd[h][reg] = 0.f; }
#pragma unroll
    for (int t = 0; t < 8; ++t) {
        int h = t >> 1;
        float vs = att_src[t * 16 + m];
        float vd = att_dst[t * 16 + m];
#pragma unroll
        for (int reg = 0; reg < 4; ++reg) {
            ps[h][reg] += acc[t][reg] * vs;
            pd[h][reg] += acc[t][reg] * vd;
        }
    }
    // reduce across the 16 lanes of this quad (cols of the head pair)
#pragma unroll
    for (int off = 8; off > 0; off >>= 1) {
#pragma unroll
        for (int h = 0; h < 4; ++h)
#pragma unroll
            for (int reg = 0; reg < 4; ++reg) {
                ps[h][reg] += __shfl_down(ps[h][reg], off, 16);
                pd[h][reg] += __shfl_down(pd[h][reg], off, 16);
            }
    }
    if (m == 0) {
#pragma unroll
        for (int reg = 0; reg < 4; ++reg) {
            int row = row0 + wrow + quad * 4 + reg;
            if (row < N) {
#pragma unroll
                for (int h = 0; h < 4; ++h) {
                    a_src[row * 4 + h] = ps[h][reg];
                    a_dst[row * 4 + h] = pd[h][reg];
                }
            }
        }
    }
}

// ---------------- CSR build: histogram + per-edge rank ----------------
__global__ __launch_bounds__(256) void hist_kernel(const int* __restrict__ src,
                                                   const int* __restrict__ dst,
                                                   int* __restrict__ counts,
                                                   int* __restrict__ rank, int E) {
    int e = blockIdx.x * 256 + threadIdx.x;
    if (e >= E) return;
    int s = src[e], d = dst[e];
    if (s != d) rank[e] = atomicAdd(&counts[d], 1);
}

__global__ __launch_bounds__(256) void reduce_kernel(const int* __restrict__ counts,
                                                     int* __restrict__ blockSums, int N) {
    __shared__ int sh[256];
    int idx = blockIdx.x * 256 + threadIdx.x;
    sh[threadIdx.x] = (idx < N) ? counts[idx] : 0;
    __syncthreads();
    for (int off = 128; off > 0; off >>= 1) {
        if (threadIdx.x < off) sh[threadIdx.x] += sh[threadIdx.x + off];
        __syncthreads();
    }
    if (threadIdx.x == 0) blockSums[blockIdx.x] = sh[0];
}

__global__ __launch_bounds__(256) void scan_top_kernel(int* __restrict__ blockSums,
                                                       int* __restrict__ blockPrefix, int nb) {
    __shared__ int sh[256];
    int t = threadIdx.x;
    sh[t] = (t < nb) ? blockSums[t] : 0;
    __syncthreads();
    for (int off = 1; off < 256; off <<= 1) {
        int v = (t >= off) ? sh[t - off] : 0;
        __syncthreads();
        sh[t] += v;
        __syncthreads();
    }
    if (t < nb) blockPrefix[t] = (t == 0) ? 0 : sh[t - 1];
}

__global__ __launch_bounds__(256) void apply_kernel(const int* __restrict__ counts,
                                                    const int* __restrict__ blockPrefix,
                                                    int* __restrict__ offsets, int N) {
    __shared__ int sh[256];
    int idx = blockIdx.x * 256 + threadIdx.x;
    int t = threadIdx.x;
    int c = (idx < N) ? counts[idx] : 0;
    sh[t] = c;
    __syncthreads();
    for (int off = 1; off < 256; off <<= 1) {
        int v = (t >= off) ? sh[t - off] : 0;
        __syncthreads();
        sh[t] += v;
        __syncthreads();
    }
    if (idx < N) offsets[idx] = sh[t] - c + blockPrefix[blockIdx.x];
}

// pure scatter: no atomics, slot = offsets[d] + rank[e]
__global__ __launch_bounds__(256) void scatter_kernel(const int* __restrict__ src,
                                                      const int* __restrict__ dst,
                                                      const int* __restrict__ offsets,
                                                      const int* __restrict__ rank,
                                                      int* __restrict__ bucket, int E) {
    int e = blockIdx.x * 256 + threadIdx.x;
    if (e >= E) return;
    int s = src[e], d = dst[e];
    if (s == d) return;
    bucket[offsets[d] + rank[e]] = s;
}

// ---------------- gather: 32 lanes/node, bf16 messages, 4x unrolled ----------------
__global__ __launch_bounds__(256) void gather_kernel(const int* __restrict__ offsets,
                                                     const int* __restrict__ counts,
                                                     const int* __restrict__ bucket,
                                                     const unsigned short* __restrict__ xlh,
                                                     const float* __restrict__ a_src,
                                                     const float* __restrict__ a_dst,
                                                     const float* __restrict__ bias,
                                                     float* __restrict__ out, int N) {
    int node = blockIdx.x * 8 + (threadIdx.x >> 5);
    int lane = threadIdx.x & 31;
    if (node >= N) return;
    const int c4 = lane * 4;
    const int h = lane >> 3;
    const float ad = a_dst[node * 4 + h];

    const int beg = offsets[node];
    const int cnt = counts[node];

    float4 acc = make_float4(0.f, 0.f, 0.f, 0.f);
    float den = 0.f;

    int j = 0;
    for (; j + 4 <= cnt; j += 4) {
        int s0 = bucket[beg + j + 0];
        int s1 = bucket[beg + j + 1];
        int s2 = bucket[beg + j + 2];
        int s3 = bucket[beg + j + 3];
        float e0 = a_src[s0 * 4 + h] + ad;
        float e1 = a_src[s1 * 4 + h] + ad;
        float e2 = a_src[s2 * 4 + h] + ad;
        float e3 = a_src[s3 * 4 + h] + ad;
        ushort4 u0 = *(const ushort4*)(xlh + (size_t)s0 * CDIM + c4);
        ushort4 u1 = *(const ushort4*)(xlh + (size_t)s1 * CDIM + c4);
        ushort4 u2 = *(const ushort4*)(xlh + (size_t)s2 * CDIM + c4);
        ushort4 u3 = *(const ushort4*)(xlh + (size_t)s3 * CDIM + c4);
        e0 = e0 > 0.f ? e0 : NEG * e0;
        e1 = e1 > 0.f ? e1 : NEG * e1;
        e2 = e2 > 0.f ? e2 : NEG * e2;
        e3 = e3 > 0.f ? e3 : NEG * e3;
        float w0 = __expf(e0), w1 = __expf(e1), w2 = __expf(e2), w3 = __expf(e3);
        acc.x += w0 * bf2f(u0.x); acc.y += w0 * bf2f(u0.y); acc.z += w0 * bf2f(u0.z); acc.w += w0 * bf2f(u0.w);
        acc.x += w1 * bf2f(u1.x); acc.y += w1 * bf2f(u1.y); acc.z += w1 * bf2f(u1.z); acc.w += w1 * bf2f(u1.w);
        acc.x += w2 * bf2f(u2.x); acc.y += w2 * bf2f(u2.y); acc.z += w2 * bf2f(u2.z); acc.w += w2 * bf2f(u2.w);
        acc.x += w3 * bf2f(u3.x); acc.y += w3 * bf2f(u3.y); acc.z += w3 * bf2f(u3.z); acc.w += w3 * bf2f(u3.w);
        den += w0 + w1 + w2 + w3;
    }
    for (; j < cnt; ++j) {
        int s = bucket[beg + j];
        float e = a_src[s * 4 + h] + ad;
        ushort4 u = *(const ushort4*)(xlh + (size_t)s * CDIM + c4);
        e = e > 0.f ? e : NEG * e;
        float w = __expf(e);
        acc.x += w * bf2f(u.x); acc.y += w * bf2f(u.y); acc.z += w * bf2f(u.z); acc.w += w * bf2f(u.w);
        den += w;
    }
    // self loop
    float es = a_src[node * 4 + h] + ad;
    es = es > 0.f ? es : NEG * es;
    float ws = __expf(es);
    ushort4 u = *(const ushort4*)(xlh + (size_t)node * CDIM + c4);
    acc.x += ws * bf2f(u.x); acc.y += ws * bf2f(u.y); acc.z += ws * bf2f(u.z); acc.w += ws * bf2f(u.w);
    den += ws;

    float inv = 1.0f / den;
    float4 b = *(const float4*)(bias + c4);
    float4 o;
    o.x = (acc.x * inv + b.x) * 0.5f;
    o.y = (acc.y * inv + b.y) * 0.5f;
    o.z = (acc.z * inv + b.z) * 0.5f;
    o.w = (acc.w * inv + b.w) * 0.5f;
    *(float4*)(out + (size_t)node * CDIM + c4) = o;
}

extern "C" void kernel_launch(void* const* d_in, const int* in_sizes, int n_in,
                              void* d_out, int out_size, void* d_ws, size_t ws_size,
                              hipStream_t stream) {
    const float* x       = (const float*)d_in[0];
    const int*   ei      = (const int*)d_in[1];
    const float* W       = (const float*)d_in[2];
    const float* att_src = (const float*)d_in[3];
    const float* att_dst = (const float*)d_in[4];
    const float* bias    = (const float*)d_in[5];
    float* out = (float*)d_out;

    const int N = in_sizes[0] / CDIM;
    const int E = in_sizes[1] / 2;
    const int nb = (N + 255) / 256;

    char* wsb = (char*)d_ws;
    unsigned short* xlh = (unsigned short*)wsb;         wsb += (size_t)N * CDIM * sizeof(unsigned short);
    float* a_src = (float*)wsb;                         wsb += (size_t)N * HEADS * sizeof(float);
    float* a_dst = (float*)wsb;                         wsb += (size_t)N * HEADS * sizeof(float);
    int* counts  = (int*)wsb;                           wsb += (size_t)N * sizeof(int);
    int* offsets = (int*)wsb;                           wsb += (size_t)N * sizeof(int);
    int* blockSums   = (int*)wsb;                       wsb += (size_t)nb * sizeof(int);
    int* blockPrefix = (int*)wsb;                       wsb += (size_t)nb * sizeof(int);
    int* rank    = (int*)wsb;                           wsb += (size_t)E * sizeof(int);
    int* bucket  = (int*)wsb;                           wsb += (size_t)E * sizeof(int);

    hipMemsetAsync(counts, 0, (size_t)N * sizeof(int), stream);

    gemm_mfma_kernel<<<(N + 63) / 64, 256, 0, stream>>>(x, W, att_src, att_dst, xlh, a_src, a_dst, N);
    hist_kernel<<<(E + 255) / 256, 256, 0, stream>>>(ei, ei + E, counts, rank, E);
    reduce_kernel<<<nb, 256, 0, stream>>>(counts, blockSums, N);
    scan_top_kernel<<<1, 256, 0, stream>>>(blockSums, blockPrefix, nb);
    apply_kernel<<<nb, 256, 0, stream>>>(counts, blockPrefix, offsets, N);
    scatter_kernel<<<(E + 255) / 256, 256, 0, stream>>>(ei, ei + E, offsets, rank, bucket, E);
    gather_kernel<<<(N + 7) / 8, 256, 0, stream>>>(offsets, counts, bucket, xlh, a_src, a_dst, bias, out, N);
}